// Round 3
// baseline (96.971 us; speedup 1.0000x reference)
//
#include <hip/hip_runtime.h>
#include <math.h>

// CRF forward: B=64, C=2, T=65536.
// Log-semiring matrix scan: alpha_t = A_t (x) alpha_{t-1},
//   A_t[i][j] = trans[i][j] + emit_t[i]
// Associative => parallel chunked scan with 2x2 transfer matrices.
// All math in base-2 logs so LSE = 1x v_exp_f32 + 1x v_log_f32.

#define T_LEN   65536
#define SEG     4096      // elements per block
#define CH_L    16        // elements per thread chunk
#define NT      256       // threads per block
#define NSEG    16        // SEG * NSEG = T_LEN
#define NBATCH  64

// __builtin_amdgcn_exp2f = v_exp_f32 (2^x); __builtin_amdgcn_logf = v_log_f32 (log2 x)
__device__ __forceinline__ float lse2(float a, float b) {
    float m = fmaxf(a, b);
    float d = fminf(a, b) - m;          // <= 0; -1e30 inputs give exp2 -> 0, no NaN
    return m + __builtin_amdgcn_logf(1.0f + __builtin_amdgcn_exp2f(d));
}

__global__ __launch_bounds__(NT) void crf_scan_kernel(
    const float* __restrict__ logits,   // (B, 2, T) flat
    const float* __restrict__ trans,    // (2,2)
    float* __restrict__ out,            // out[0]=loss, out[1..]=decoded
    float4* __restrict__ wsM)           // 1024 chunk matrices
{
    __shared__ float s0[SEG + SEG / 16];   // +1 pad per 16 -> stride-17 reads conflict-free
    __shared__ float s1[SEG + SEG / 16];
    __shared__ float4 red[NT];

    const int blk = blockIdx.x;         // 0..1023
    const int b   = blk >> 4;           // batch
    const int seg = blk & (NSEG - 1);   // segment within batch
    const int tid = threadIdx.x;
    const float K = 1.4426950408889634f;    // log2(e)

    const float* l0 = logits + (size_t)b * (2 * T_LEN) + (size_t)seg * SEG;
    const float* l1 = l0 + T_LEN;
    float* dec = out + 1 + (size_t)b * T_LEN + (size_t)seg * SEG;

    // ---- Phase A: coalesced load -> LDS (scaled to base-2), fused argmax write ----
    #pragma unroll
    for (int it = 0; it < SEG / (NT * 4); ++it) {   // 4 iterations
        const int idx = it * NT * 4 + tid * 4;
        const float4 a = *(const float4*)(l0 + idx);
        const float4 c = *(const float4*)(l1 + idx);
        dec[idx + 0] = (a.x >= c.x) ? 0.0f : 1.0f;
        dec[idx + 1] = (a.y >= c.y) ? 0.0f : 1.0f;
        dec[idx + 2] = (a.z >= c.z) ? 0.0f : 1.0f;
        dec[idx + 3] = (a.w >= c.w) ? 0.0f : 1.0f;
        const int li = idx + (idx >> 4);    // swizzle: groups of 4 stay contiguous
        s0[li + 0] = a.x * K; s0[li + 1] = a.y * K; s0[li + 2] = a.z * K; s0[li + 3] = a.w * K;
        s1[li + 0] = c.x * K; s1[li + 1] = c.y * K; s1[li + 2] = c.z * K; s1[li + 3] = c.w * K;
    }

    const float t00 = trans[0] * K, t01 = trans[1] * K;
    const float t10 = trans[2] * K, t11 = trans[3] * K;
    __syncthreads();

    // ---- Phase B: per-thread sequential scan over CH_L steps (2x2 matrix mode) ----
    const int lb = tid * 17;            // == (tid*16) + ((tid*16)>>4)
    float e0 = s0[lb], e1 = s1[lb];
    float m00, m01, m10, m11;
    if (seg == 0 && tid == 0) {
        // global t=0: initial vector alpha0 = emit_0 as diagonal "matrix"
        m00 = e0; m11 = e1; m01 = -1e30f; m10 = -1e30f;
    } else {
        m00 = t00 + e0; m01 = t01 + e0;
        m10 = t10 + e1; m11 = t11 + e1;
    }
    #pragma unroll
    for (int j = 1; j < CH_L; ++j) {
        e0 = s0[lb + j]; e1 = s1[lb + j];
        float n00 = e0 + lse2(t00 + m00, t01 + m10);
        float n01 = e0 + lse2(t00 + m01, t01 + m11);
        float n10 = e1 + lse2(t10 + m00, t11 + m10);
        float n11 = e1 + lse2(t10 + m01, t11 + m11);
        m00 = n00; m01 = n01; m10 = n10; m11 = n11;
    }

    // ---- Phase C: block tree-reduce 256 matrices (later (x) earlier) ----
    red[tid] = make_float4(m00, m01, m10, m11);
    __syncthreads();
    for (int s = NT / 2; s >= 1; s >>= 1) {
        if (tid < s) {
            float4 A  = red[tid + s];   // later chunk
            float4 Bm = red[tid];       // earlier chunk
            float c00 = lse2(A.x + Bm.x, A.y + Bm.z);
            float c01 = lse2(A.x + Bm.y, A.y + Bm.w);
            float c10 = lse2(A.z + Bm.x, A.w + Bm.z);
            float c11 = lse2(A.z + Bm.y, A.w + Bm.w);
            red[tid] = make_float4(c00, c01, c10, c11);
        }
        __syncthreads();
    }
    if (tid == 0) wsM[blk] = red[0];
}

__global__ __launch_bounds__(64) void crf_final_kernel(
    const float4* __restrict__ wsM, float* __restrict__ out)
{
    const int b = threadIdx.x;          // one lane per batch, exactly one wave
    float4 Acc = wsM[b * NSEG];
    #pragma unroll
    for (int s = 1; s < NSEG; ++s) {
        float4 A = wsM[b * NSEG + s];   // later
        float c00 = lse2(A.x + Acc.x, A.y + Acc.z);
        float c01 = lse2(A.x + Acc.y, A.y + Acc.w);
        float c10 = lse2(A.z + Acc.x, A.w + Acc.z);
        float c11 = lse2(A.z + Acc.y, A.w + Acc.w);
        Acc = make_float4(c00, c01, c10, c11);
    }
    // alpha_final[i] = LSE_k M[i][k]; LL2_b = LSE_i alpha_final[i]
    float ll2 = lse2(lse2(Acc.x, Acc.y), lse2(Acc.z, Acc.w));
    #pragma unroll
    for (int off = 32; off >= 1; off >>= 1) ll2 += __shfl_xor(ll2, off);
    if (b == 0) out[0] = -(0.6931471805599453f * ll2) * (1.0f / (float)NBATCH);
}

extern "C" void kernel_launch(void* const* d_in, const int* in_sizes, int n_in,
                              void* d_out, int out_size, void* d_ws, size_t ws_size,
                              hipStream_t stream) {
    const float* logits = (const float*)d_in[0];
    // d_in[1] = mask: all-ones and unused by the reference computation
    const float* trans  = (const float*)d_in[2];
    float* out  = (float*)d_out;
    float4* wsM = (float4*)d_ws;    // 1024 * 16 B = 16 KiB

    crf_scan_kernel<<<NBATCH * NSEG, NT, 0, stream>>>(logits, trans, out, wsM);
    crf_final_kernel<<<1, 64, 0, stream>>>(wsM, out);
}